// Round 9
// baseline (208.067 us; speedup 1.0000x reference)
//
#include <hip/hip_runtime.h>

typedef __bf16 bf16;
typedef __attribute__((ext_vector_type(4))) __bf16 bf16x4;
typedef __attribute__((ext_vector_type(8))) __bf16 bf16x8;
typedef __attribute__((ext_vector_type(4))) float f32x4;

static __device__ __forceinline__ f32x4 mfma_16x16x32(bf16x8 a, bf16x8 b, f32x4 c) {
    return __builtin_amdgcn_mfma_f32_16x16x32_bf16(a, b, c, 0, 0, 0);
}

static __device__ __forceinline__ bf16x8 load8(const float* p) {
    f32x4 a = *(const f32x4*)p;
    f32x4 b = *(const f32x4*)(p + 4);
    bf16x8 r;
    r[0] = (bf16)a[0]; r[1] = (bf16)a[1]; r[2] = (bf16)a[2]; r[3] = (bf16)a[3];
    r[4] = (bf16)b[0]; r[5] = (bf16)b[1]; r[6] = (bf16)b[2]; r[7] = (bf16)b[3];
    return r;
}

// async global->LDS, 16B per lane; LDS dest = wave-uniform base + lane*16
static __device__ __forceinline__ void gload_lds16(const void* g, void* l) {
    __builtin_amdgcn_global_load_lds(
        (const __attribute__((address_space(1))) void*)g,
        (__attribute__((address_space(3))) void*)l, 16, 0, 0);
}

// Q pre-scale: (1/sqrt(1024)) * log2(e)  -> softmax via exp2 (1 v_exp_f32)
#define QSCALE 0.0450842200277801f

// ---------------------------------------------------------------------------
// Prep: fused elementwise casts (l_h, v_h -> bf16) + 4 weight
// transpose-converts (f32 (K,N) -> bf16 (N,K)). q-weight pre-scaled by
// QSCALE so attn computes exp2(s) directly (base-2 softmax == base-e).
// ---------------------------------------------------------------------------
__global__ __launch_bounds__(256) void prep_kernel(
    const float* __restrict__ l_h, const float* __restrict__ v_h,
    const float* __restrict__ w0, const float* __restrict__ w1,
    const float* __restrict__ w2, const float* __restrict__ w3,
    bf16* __restrict__ l_bf, bf16* __restrict__ v_bf,
    bf16* __restrict__ dq, bf16* __restrict__ dkv, bf16* __restrict__ dov)
{
    const int id = blockIdx.x;
    if (id < 4096) {
        const float* s = (id < 2048) ? l_h : v_h;
        bf16*       d = (id < 2048) ? l_bf : v_bf;
        const int   bb = (id < 2048) ? id : id - 2048;
        const size_t i = ((size_t)bb * 256 + threadIdx.x) * 8;
        *(bf16x8*)(d + i) = load8(s + i);
        return;
    }
    const int widx = id - 4096;
    const int z    = widx >> 8;
    const int rem  = widx & 255;
    const int j0   = (rem & 15) * 64;    // n tile
    const int i0   = (rem >> 4) * 64;    // k tile
    const float* src; bf16* dst;
    switch (z) {
        case 0:  src = w0; dst = dq; break;
        case 1:  src = w1; dst = dkv; break;
        case 2:  src = w2; dst = dkv + (size_t)1024 * 1024; break;
        default: src = w3; dst = dov; break;
    }
    const float wscale = (z == 0) ? QSCALE : 1.0f;
    __shared__ float T[64][65];
    const int tx = threadIdx.x & 15;
    const int ty = threadIdx.x >> 4;
    #pragma unroll
    for (int it = 0; it < 4; ++it) {
        f32x4 v = *(const f32x4*)(src + (size_t)(i0 + ty + it * 16) * 1024 + j0 + tx * 4);
        T[ty + it * 16][tx * 4 + 0] = v[0];
        T[ty + it * 16][tx * 4 + 1] = v[1];
        T[ty + it * 16][tx * 4 + 2] = v[2];
        T[ty + it * 16][tx * 4 + 3] = v[3];
    }
    __syncthreads();
    #pragma unroll
    for (int it = 0; it < 4; ++it) {
        const int jj = ty + it * 16;
        bf16x4 o;
        o[0] = (bf16)(T[tx * 4 + 0][jj] * wscale);
        o[1] = (bf16)(T[tx * 4 + 1][jj] * wscale);
        o[2] = (bf16)(T[tx * 4 + 2][jj] * wscale);
        o[3] = (bf16)(T[tx * 4 + 3][jj] * wscale);
        *(bf16x4*)(dst + (size_t)(j0 + jj) * 1024 + i0 + tx * 4) = o;
    }
}

// ---------------------------------------------------------------------------
// Fused Q+KV projection, m97 128x128 structure. grid (24, 32): x<8 -> Q
// (weights pre-scaled by QSCALE); x>=8 -> KV. 768 blocks = 3/CU.
// ---------------------------------------------------------------------------
__global__ __launch_bounds__(256, 2) void proj128_kernel(
    const bf16* __restrict__ l_bf, const bf16* __restrict__ v_bf,
    const bf16* __restrict__ QWt,  const bf16* __restrict__ KVWt,
    const float* __restrict__ q_b, const float* __restrict__ k_b,
    const float* __restrict__ v_b,
    bf16* __restrict__ Qh, bf16* __restrict__ Kh, bf16* __restrict__ Vt)
{
    __shared__ __align__(16) bf16 As[128][32];
    __shared__ __align__(16) bf16 Bs[128][32];

    const int t    = threadIdx.x;
    const int lane = t & 63;
    const int wave = t >> 6;
    const int wm   = wave & 1;
    const int wn   = wave >> 1;
    const int l15  = lane & 15;
    const int quad = lane >> 4;

    const bool isQ = blockIdx.x < 8;
    const bf16* A  = isQ ? l_bf : v_bf;
    const bf16* Bt = isQ ? QWt  : KVWt;
    const int  gn0 = (isQ ? blockIdx.x : blockIdx.x - 8) * 128;
    const int  gm0 = blockIdx.y * 128;
    const int  K   = 1024;

    const int srow    = lane >> 2;
    const int chunk_g = (lane & 3) ^ ((srow >> 1) & 3);
    const size_t aoff = (size_t)(gm0 + wave * 32 + srow) * K + chunk_g * 8;
    const size_t boff = (size_t)(gn0 + wave * 32 + srow) * K + chunk_g * 8;

    f32x4 acc[4][4];
    #pragma unroll
    for (int i = 0; i < 4; ++i)
        #pragma unroll
        for (int j = 0; j < 4; ++j)
            acc[i][j] = (f32x4){0.f, 0.f, 0.f, 0.f};

    for (int k0 = 0; k0 < K; k0 += 32) {
        #pragma unroll
        for (int q = 0; q < 2; ++q) {
            gload_lds16(A  + aoff + (size_t)q * 16 * K + k0, &As[wave * 32 + q * 16][0]);
            gload_lds16(Bt + boff + (size_t)q * 16 * K + k0, &Bs[wave * 32 + q * 16][0]);
        }
        __syncthreads();

        bf16x8 af[4], bfr[4];
        #pragma unroll
        for (int mt = 0; mt < 4; ++mt) {
            const int row = wm * 64 + mt * 16 + l15;
            af[mt] = *(const bf16x8*)(&As[row][(quad ^ ((row >> 1) & 3)) * 8]);
        }
        #pragma unroll
        for (int nt = 0; nt < 4; ++nt) {
            const int row = wn * 64 + nt * 16 + l15;
            bfr[nt] = *(const bf16x8*)(&Bs[row][(quad ^ ((row >> 1) & 3)) * 8]);
        }
        #pragma unroll
        for (int mt = 0; mt < 4; ++mt)
            #pragma unroll
            for (int nt = 0; nt < 4; ++nt)
                acc[mt][nt] = mfma_16x16x32(af[mt], bfr[nt], acc[mt][nt]);

        __syncthreads();
    }

    #pragma unroll
    for (int nt = 0; nt < 4; ++nt) {
        const int col = gn0 + wn * 64 + nt * 16 + l15;
        float bb; bf16* dst; bool hm;
        if (isQ)             { bb = q_b[col] * QSCALE;   dst = Qh; hm = true;  }
        else if (col < 1024) { bb = k_b[col];            dst = Kh; hm = true;  }
        else                 { bb = v_b[col - 1024];     dst = Vt; hm = false; }
        #pragma unroll
        for (int mt = 0; mt < 4; ++mt) {
            #pragma unroll
            for (int r = 0; r < 4; ++r) {
                const int row = gm0 + wm * 64 + mt * 16 + quad * 4 + r;
                const float v = acc[mt][nt][r] + bb;
                if (hm) {
                    const size_t idx =
                        ((size_t)((row >> 10) * 16 + (col >> 6)) * 1024 +
                         (row & 1023)) * 64 + (col & 63);
                    dst[idx] = (bf16)v;
                } else {
                    const int vc = col - 1024;
                    const size_t idx =
                        ((size_t)((row >> 10) * 16 + (vc >> 6)) * 64 +
                         (vc & 63)) * 1024 + (row & 1023);
                    dst[idx] = (bf16)v;
                }
            }
        }
    }
}

// ---------------------------------------------------------------------------
// Output projection, split-K=2 at the full 128x128/16-MFMA structure:
// grid (8, 32, 2) = 512 blocks = 2/CU, 16 k-iters per block. f32 partials
// (no bias) go to dead ws regions; reduce_kernel adds them + bias.
// ---------------------------------------------------------------------------
__global__ __launch_bounds__(256, 2) void ogemm_split_kernel(
    const bf16* __restrict__ Aw, const bf16* __restrict__ OWt,
    float* __restrict__ P0, float* __restrict__ P1)
{
    __shared__ __align__(16) bf16 As[128][32];
    __shared__ __align__(16) bf16 Bs[128][32];

    const int t    = threadIdx.x;
    const int lane = t & 63;
    const int wave = t >> 6;
    const int wm   = wave & 1;
    const int wn   = wave >> 1;
    const int l15  = lane & 15;
    const int quad = lane >> 4;

    const int gn0  = blockIdx.x * 128;
    const int gm0  = blockIdx.y * 128;
    const int K    = 1024;
    const int koff = blockIdx.z * 512;
    float* outp    = blockIdx.z ? P1 : P0;

    const int srow    = lane >> 2;
    const int chunk_g = (lane & 3) ^ ((srow >> 1) & 3);
    const size_t aoff = (size_t)(gm0 + wave * 32 + srow) * K + koff + chunk_g * 8;
    const size_t boff = (size_t)(gn0 + wave * 32 + srow) * K + koff + chunk_g * 8;

    f32x4 acc[4][4];
    #pragma unroll
    for (int i = 0; i < 4; ++i)
        #pragma unroll
        for (int j = 0; j < 4; ++j)
            acc[i][j] = (f32x4){0.f, 0.f, 0.f, 0.f};

    for (int k0 = 0; k0 < 512; k0 += 32) {
        #pragma unroll
        for (int q = 0; q < 2; ++q) {
            gload_lds16(Aw  + aoff + (size_t)q * 16 * K + k0, &As[wave * 32 + q * 16][0]);
            gload_lds16(OWt + boff + (size_t)q * 16 * K + k0, &Bs[wave * 32 + q * 16][0]);
        }
        __syncthreads();

        bf16x8 af[4], bfr[4];
        #pragma unroll
        for (int mt = 0; mt < 4; ++mt) {
            const int row = wm * 64 + mt * 16 + l15;
            af[mt] = *(const bf16x8*)(&As[row][(quad ^ ((row >> 1) & 3)) * 8]);
        }
        #pragma unroll
        for (int nt = 0; nt < 4; ++nt) {
            const int row = wn * 64 + nt * 16 + l15;
            bfr[nt] = *(const bf16x8*)(&Bs[row][(quad ^ ((row >> 1) & 3)) * 8]);
        }
        #pragma unroll
        for (int mt = 0; mt < 4; ++mt)
            #pragma unroll
            for (int nt = 0; nt < 4; ++nt)
                acc[mt][nt] = mfma_16x16x32(af[mt], bfr[nt], acc[mt][nt]);

        __syncthreads();
    }

    #pragma unroll
    for (int nt = 0; nt < 4; ++nt) {
        const int col = gn0 + wn * 64 + nt * 16 + l15;
        #pragma unroll
        for (int mt = 0; mt < 4; ++mt) {
            #pragma unroll
            for (int r = 0; r < 4; ++r) {
                const int row = gm0 + wm * 64 + mt * 16 + quad * 4 + r;
                outp[(size_t)row * 1024 + col] = acc[mt][nt][r];
            }
        }
    }
}

// out = P0 + P1 + bias (f32x4). grid 4096 blocks x 256 thr x 4 elems.
__global__ __launch_bounds__(256) void reduce_kernel(
    const float* __restrict__ P0, const float* __restrict__ P1,
    const float* __restrict__ o_b, float* __restrict__ C)
{
    const size_t i = ((size_t)blockIdx.x * 256 + threadIdx.x) * 4;
    f32x4 a = *(const f32x4*)(P0 + i);
    f32x4 b = *(const f32x4*)(P1 + i);
    f32x4 bb = *(const f32x4*)(o_b + (i & 1023));
    f32x4 o;
    #pragma unroll
    for (int j = 0; j < 4; ++j) o[j] = a[j] + b[j] + bb[j];
    *(f32x4*)(C + i) = o;
}

// ---------------------------------------------------------------------------
// Attention v6 (round-8 structure) + exp2: block = (head, 128 q-rows),
// 4 waves, wave owns 32 q over the FULL kv range. K/V^T chunks staged once
// per block into double-buffered LDS (global_load_lds, XOR unit-swizzle),
// shared by 4 waves; 1 barrier/chunk; next chunk prefetched post-barrier.
// Q pre-scaled by QSCALE -> p = exp2(s) (single v_exp_f32 per score).
// ---------------------------------------------------------------------------
__global__ __launch_bounds__(256) void attn_kernel(
    const bf16* __restrict__ Q, const bf16* __restrict__ K,
    const bf16* __restrict__ V, bf16* __restrict__ O)
{
    const int t    = threadIdx.x;
    const int lane = t & 63;
    const int wave = t >> 6;
    const int l15  = lane & 15;
    const int quad = lane >> 4;

    const int head = blockIdx.x;        // b*16 + h
    const int q0   = blockIdx.y * 128;
    const int b    = head >> 4;
    const int h    = head & 15;

    __shared__ __align__(16) bf16 Kb[2][64][64];   // [buf][kv][hd]
    __shared__ __align__(16) bf16 Vb[2][64][64];   // [buf][hd][kv]
    __shared__ __align__(16) bf16 P[4][32][72];    // per-wave P, pad 64->72

    const bf16* Qp  = Q + ((size_t)head * 1024 + q0 + wave * 32) * 64;
    const bf16* Kp  = K + (size_t)head * 1024 * 64;
    const bf16* Vtp = V + (size_t)head * 64 * 1024;

    const int r8  = lane >> 3;          // 0..7
    const int c8  = lane & 7;           // 0..7
    const int swz = (c8 ^ r8) * 8;      // fetch-side XOR unit swizzle

    bf16x8 aq[2][2];
    #pragma unroll
    for (int mt = 0; mt < 2; ++mt)
        #pragma unroll
        for (int kc = 0; kc < 2; ++kc)
            aq[mt][kc] = *(const bf16x8*)(Qp + (mt * 16 + l15) * 64 + kc * 32 + quad * 8);

    f32x4 oacc[2][4];
    #pragma unroll
    for (int mt = 0; mt < 2; ++mt)
        #pragma unroll
        for (int nt = 0; nt < 4; ++nt)
            oacc[mt][nt] = (f32x4){0.f, 0.f, 0.f, 0.f};
    float lsum[2][4];
    #pragma unroll
    for (int mt = 0; mt < 2; ++mt)
        #pragma unroll
        for (int r = 0; r < 4; ++r) lsum[mt][r] = 0.f;

    #define STAGE(c, buf)                                                          \
        {                                                                          \
            const int kv0_ = (c) * 64;                                             \
            _Pragma("unroll")                                                      \
            for (int g = 0; g < 2; ++g) {                                          \
                const int R = wave * 16 + g * 8;                                   \
                gload_lds16(Kp + (size_t)(kv0_ + R + r8) * 64 + swz,               \
                            &Kb[buf][R][0]);                                       \
                gload_lds16(Vtp + (size_t)(R + r8) * 1024 + kv0_ + swz,            \
                            &Vb[buf][R][0]);                                       \
            }                                                                      \
        }

    STAGE(0, 0);

    const int sw = l15 & 7;             // read-side swizzle (row & 7)

    for (int c = 0; c < 16; ++c) {
        const int buf = c & 1;
        __syncthreads();
        if (c + 1 < 16) STAGE(c + 1, buf ^ 1);

        #pragma unroll
        for (int nt = 0; nt < 4; ++nt) {
            const bf16* krow = &Kb[buf][nt * 16 + l15][0];
            bf16x8 bk0 = *(const bf16x8*)(krow + (quad ^ sw) * 8);
            bf16x8 bk1 = *(const bf16x8*)(krow + ((quad + 4) ^ sw) * 8);
            #pragma unroll
            for (int mt = 0; mt < 2; ++mt) {
                f32x4 s = (f32x4){0.f, 0.f, 0.f, 0.f};
                s = mfma_16x16x32(aq[mt][0], bk0, s);
                s = mfma_16x16x32(aq[mt][1], bk1, s);
                #pragma unroll
                for (int r = 0; r < 4; ++r) {
                    const float e = exp2f(s[r]);
                    lsum[mt][r] += e;
                    P[wave][mt * 16 + quad * 4 + r][nt * 16 + l15] = (bf16)e;
                }
            }
        }

        #pragma unroll
        for (int mt = 0; mt < 2; ++mt) {
            bf16x8 pa0 = *(const bf16x8*)(&P[wave][mt * 16 + l15][quad * 8]);
            bf16x8 pa1 = *(const bf16x8*)(&P[wave][mt * 16 + l15][32 + quad * 8]);
            #pragma unroll
            for (int nt = 0; nt < 4; ++nt) {
                const bf16* vrow = &Vb[buf][nt * 16 + l15][0];
                bf16x8 bv0 = *(const bf16x8*)(vrow + (quad ^ sw) * 8);
                bf16x8 bv1 = *(const bf16x8*)(vrow + ((quad + 4) ^ sw) * 8);
                oacc[mt][nt] = mfma_16x16x32(pa0, bv0, oacc[mt][nt]);
                oacc[mt][nt] = mfma_16x16x32(pa1, bv1, oacc[mt][nt]);
            }
        }
    }
    #undef STAGE

    #pragma unroll
    for (int off = 1; off <= 8; off <<= 1)
        #pragma unroll
        for (int mt = 0; mt < 2; ++mt)
            #pragma unroll
            for (int r = 0; r < 4; ++r)
                lsum[mt][r] += __shfl_xor(lsum[mt][r], off, 64);

    #pragma unroll
    for (int mt = 0; mt < 2; ++mt) {
        const float invs[4] = {1.0f / lsum[mt][0], 1.0f / lsum[mt][1],
                               1.0f / lsum[mt][2], 1.0f / lsum[mt][3]};
        #pragma unroll
        for (int nt = 0; nt < 4; ++nt) {
            #pragma unroll
            for (int r = 0; r < 4; ++r) {
                const int row = q0 + wave * 32 + mt * 16 + quad * 4 + r;
                O[((size_t)b * 1024 + row) * 1024 + h * 64 + nt * 16 + l15] =
                    (bf16)(oacc[mt][nt][r] * invs[r]);
            }
        }
    }
}

// ---------------------------------------------------------------------------
// Host launcher — inputs/outputs FLOAT32 per reference; bf16 internal.
// ws (bf16 elems): l_bf 4M | v_bf 4M | QWt 1M | KVWt 2M | OWt 1M |
//                  Qh 4M | Kh 4M | Vt 4M | Aw 4M = 28M = 56 MB
// ogemm f32 partials overlay DEAD regions: P0 on l_bf+v_bf (16 MB),
// P1 on Qh+Kh (16 MB) — both unused after attn.
// ---------------------------------------------------------------------------
extern "C" void kernel_launch(void* const* d_in, const int* in_sizes, int n_in,
                              void* d_out, int out_size, void* d_ws, size_t ws_size,
                              hipStream_t stream)
{
    const float* v_h = (const float*)d_in[0];
    const float* l_h = (const float*)d_in[1];
    const float* q_w = (const float*)d_in[2];
    const float* q_b = (const float*)d_in[3];
    const float* k_w = (const float*)d_in[4];
    const float* k_b = (const float*)d_in[5];
    const float* v_w = (const float*)d_in[6];
    const float* v_b = (const float*)d_in[7];
    const float* o_w = (const float*)d_in[8];
    const float* o_b = (const float*)d_in[9];
    float* out = (float*)d_out;

    const size_t SZ = (size_t)4096 * 1024;      // 4M
    const size_t WZ = (size_t)1024 * 1024;      // 1M

    bf16* l_bf = (bf16*)d_ws;
    bf16* v_bf = l_bf + SZ;
    bf16* QWt  = v_bf + SZ;
    bf16* KVWt = QWt + WZ;
    bf16* OWt  = KVWt + 2 * WZ;
    bf16* Qh   = OWt + WZ;      // (b,h,ls,64), pre-scaled by QSCALE
    bf16* Kh   = Qh + SZ;       // (b,h,vs,64)
    bf16* Vt   = Kh + SZ;       // (b,h,64,vs)
    bf16* Aw   = Vt + SZ;       // (b,ls,1024)

    float* KP0 = (float*)l_bf;  // 4M f32 over l_bf+v_bf (dead after proj)
    float* KP1 = (float*)Qh;    // 4M f32 over Qh+Kh (dead after attn)

    prep_kernel<<<dim3(5120), 256, 0, stream>>>(
        l_h, v_h, q_w, k_w, v_w, o_w, l_bf, v_bf, QWt, KVWt, OWt);

    proj128_kernel<<<dim3(24, 32), 256, 0, stream>>>(
        l_bf, v_bf, QWt, KVWt, q_b, k_b, v_b, Qh, Kh, Vt);

    attn_kernel<<<dim3(64, 8), 256, 0, stream>>>(Qh, Kh, Vt, Aw);

    ogemm_split_kernel<<<dim3(8, 32, 2), 256, 0, stream>>>(Aw, OWt, KP0, KP1);

    reduce_kernel<<<dim3(4096), 256, 0, stream>>>(KP0, KP1, o_b, out);

    (void)in_sizes; (void)n_in; (void)out_size; (void)ws_size;
}

// Round 10
// 193.539 us; speedup vs baseline: 1.0751x; 1.0751x over previous
//
#include <hip/hip_runtime.h>

typedef __bf16 bf16;
typedef __attribute__((ext_vector_type(4))) __bf16 bf16x4;
typedef __attribute__((ext_vector_type(8))) __bf16 bf16x8;
typedef __attribute__((ext_vector_type(4))) float f32x4;

static __device__ __forceinline__ f32x4 mfma_16x16x32(bf16x8 a, bf16x8 b, f32x4 c) {
    return __builtin_amdgcn_mfma_f32_16x16x32_bf16(a, b, c, 0, 0, 0);
}

static __device__ __forceinline__ bf16x8 load8(const float* p) {
    f32x4 a = *(const f32x4*)p;
    f32x4 b = *(const f32x4*)(p + 4);
    bf16x8 r;
    r[0] = (bf16)a[0]; r[1] = (bf16)a[1]; r[2] = (bf16)a[2]; r[3] = (bf16)a[3];
    r[4] = (bf16)b[0]; r[5] = (bf16)b[1]; r[6] = (bf16)b[2]; r[7] = (bf16)b[3];
    return r;
}

// async global->LDS, 16B per lane; LDS dest = wave-uniform base + lane*16
static __device__ __forceinline__ void gload_lds16(const void* g, void* l) {
    __builtin_amdgcn_global_load_lds(
        (const __attribute__((address_space(1))) void*)g,
        (__attribute__((address_space(3))) void*)l, 16, 0, 0);
}

// Q pre-scale: (1/sqrt(1024)) * log2(e)  -> softmax via raw v_exp_f32 (2^x)
#define QSCALE 0.0450842200277801f

// ---------------------------------------------------------------------------
// Prep: fused elementwise casts (l_h, v_h -> bf16) + 4 weight
// transpose-converts (f32 (K,N) -> bf16 (N,K)). q-weight pre-scaled by
// QSCALE so attn computes 2^s directly (base-2 softmax == base-e).
// ---------------------------------------------------------------------------
__global__ __launch_bounds__(256) void prep_kernel(
    const float* __restrict__ l_h, const float* __restrict__ v_h,
    const float* __restrict__ w0, const float* __restrict__ w1,
    const float* __restrict__ w2, const float* __restrict__ w3,
    bf16* __restrict__ l_bf, bf16* __restrict__ v_bf,
    bf16* __restrict__ dq, bf16* __restrict__ dkv, bf16* __restrict__ dov)
{
    const int id = blockIdx.x;
    if (id < 4096) {
        const float* s = (id < 2048) ? l_h : v_h;
        bf16*       d = (id < 2048) ? l_bf : v_bf;
        const int   bb = (id < 2048) ? id : id - 2048;
        const size_t i = ((size_t)bb * 256 + threadIdx.x) * 8;
        *(bf16x8*)(d + i) = load8(s + i);
        return;
    }
    const int widx = id - 4096;
    const int z    = widx >> 8;
    const int rem  = widx & 255;
    const int j0   = (rem & 15) * 64;    // n tile
    const int i0   = (rem >> 4) * 64;    // k tile
    const float* src; bf16* dst;
    switch (z) {
        case 0:  src = w0; dst = dq; break;
        case 1:  src = w1; dst = dkv; break;
        case 2:  src = w2; dst = dkv + (size_t)1024 * 1024; break;
        default: src = w3; dst = dov; break;
    }
    const float wscale = (z == 0) ? QSCALE : 1.0f;
    __shared__ float T[64][65];
    const int tx = threadIdx.x & 15;
    const int ty = threadIdx.x >> 4;
    #pragma unroll
    for (int it = 0; it < 4; ++it) {
        f32x4 v = *(const f32x4*)(src + (size_t)(i0 + ty + it * 16) * 1024 + j0 + tx * 4);
        T[ty + it * 16][tx * 4 + 0] = v[0];
        T[ty + it * 16][tx * 4 + 1] = v[1];
        T[ty + it * 16][tx * 4 + 2] = v[2];
        T[ty + it * 16][tx * 4 + 3] = v[3];
    }
    __syncthreads();
    #pragma unroll
    for (int it = 0; it < 4; ++it) {
        const int jj = ty + it * 16;
        bf16x4 o;
        o[0] = (bf16)(T[tx * 4 + 0][jj] * wscale);
        o[1] = (bf16)(T[tx * 4 + 1][jj] * wscale);
        o[2] = (bf16)(T[tx * 4 + 2][jj] * wscale);
        o[3] = (bf16)(T[tx * 4 + 3][jj] * wscale);
        *(bf16x4*)(dst + (size_t)(j0 + jj) * 1024 + i0 + tx * 4) = o;
    }
}

// ---------------------------------------------------------------------------
// Fused Q+KV projection, m97 128x128 structure. grid (24, 32): x<8 -> Q
// (weights pre-scaled by QSCALE); x>=8 -> KV. 768 blocks.
// __launch_bounds__(256,3): 3 blocks/CU co-resident (120 unified VGPR < 170)
// -> single wave-pass, no 256-block tail (r8 ran at 2/CU, Occ 25.9%).
// ---------------------------------------------------------------------------
__global__ __launch_bounds__(256, 3) void proj128_kernel(
    const bf16* __restrict__ l_bf, const bf16* __restrict__ v_bf,
    const bf16* __restrict__ QWt,  const bf16* __restrict__ KVWt,
    const float* __restrict__ q_b, const float* __restrict__ k_b,
    const float* __restrict__ v_b,
    bf16* __restrict__ Qh, bf16* __restrict__ Kh, bf16* __restrict__ Vt)
{
    __shared__ __align__(16) bf16 As[128][32];
    __shared__ __align__(16) bf16 Bs[128][32];

    const int t    = threadIdx.x;
    const int lane = t & 63;
    const int wave = t >> 6;
    const int wm   = wave & 1;
    const int wn   = wave >> 1;
    const int l15  = lane & 15;
    const int quad = lane >> 4;

    const bool isQ = blockIdx.x < 8;
    const bf16* A  = isQ ? l_bf : v_bf;
    const bf16* Bt = isQ ? QWt  : KVWt;
    const int  gn0 = (isQ ? blockIdx.x : blockIdx.x - 8) * 128;
    const int  gm0 = blockIdx.y * 128;
    const int  K   = 1024;

    const int srow    = lane >> 2;
    const int chunk_g = (lane & 3) ^ ((srow >> 1) & 3);
    const size_t aoff = (size_t)(gm0 + wave * 32 + srow) * K + chunk_g * 8;
    const size_t boff = (size_t)(gn0 + wave * 32 + srow) * K + chunk_g * 8;

    f32x4 acc[4][4];
    #pragma unroll
    for (int i = 0; i < 4; ++i)
        #pragma unroll
        for (int j = 0; j < 4; ++j)
            acc[i][j] = (f32x4){0.f, 0.f, 0.f, 0.f};

    for (int k0 = 0; k0 < K; k0 += 32) {
        #pragma unroll
        for (int q = 0; q < 2; ++q) {
            gload_lds16(A  + aoff + (size_t)q * 16 * K + k0, &As[wave * 32 + q * 16][0]);
            gload_lds16(Bt + boff + (size_t)q * 16 * K + k0, &Bs[wave * 32 + q * 16][0]);
        }
        __syncthreads();

        bf16x8 af[4], bfr[4];
        #pragma unroll
        for (int mt = 0; mt < 4; ++mt) {
            const int row = wm * 64 + mt * 16 + l15;
            af[mt] = *(const bf16x8*)(&As[row][(quad ^ ((row >> 1) & 3)) * 8]);
        }
        #pragma unroll
        for (int nt = 0; nt < 4; ++nt) {
            const int row = wn * 64 + nt * 16 + l15;
            bfr[nt] = *(const bf16x8*)(&Bs[row][(quad ^ ((row >> 1) & 3)) * 8]);
        }
        #pragma unroll
        for (int mt = 0; mt < 4; ++mt)
            #pragma unroll
            for (int nt = 0; nt < 4; ++nt)
                acc[mt][nt] = mfma_16x16x32(af[mt], bfr[nt], acc[mt][nt]);

        __syncthreads();
    }

    #pragma unroll
    for (int nt = 0; nt < 4; ++nt) {
        const int col = gn0 + wn * 64 + nt * 16 + l15;
        float bb; bf16* dst; bool hm;
        if (isQ)             { bb = q_b[col] * QSCALE;   dst = Qh; hm = true;  }
        else if (col < 1024) { bb = k_b[col];            dst = Kh; hm = true;  }
        else                 { bb = v_b[col - 1024];     dst = Vt; hm = false; }
        #pragma unroll
        for (int mt = 0; mt < 4; ++mt) {
            #pragma unroll
            for (int r = 0; r < 4; ++r) {
                const int row = gm0 + wm * 64 + mt * 16 + quad * 4 + r;
                const float v = acc[mt][nt][r] + bb;
                if (hm) {
                    const size_t idx =
                        ((size_t)((row >> 10) * 16 + (col >> 6)) * 1024 +
                         (row & 1023)) * 64 + (col & 63);
                    dst[idx] = (bf16)v;
                } else {
                    const int vc = col - 1024;
                    const size_t idx =
                        ((size_t)((row >> 10) * 16 + (vc >> 6)) * 64 +
                         (vc & 63)) * 1024 + (row & 1023);
                    dst[idx] = (bf16)v;
                }
            }
        }
    }
}

// ---------------------------------------------------------------------------
// 128x64 GEMM core (BK=32, 4 waves 2x2, acc 4x2) for the output projection.
// ---------------------------------------------------------------------------
static __device__ __forceinline__ void gemm_core_128x64(
    const bf16* __restrict__ A, const bf16* __restrict__ Bt, int K,
    int gm0, int gn0, bf16 (*As)[32], bf16 (*Bs)[32], f32x4 acc[4][2])
{
    const int t    = threadIdx.x;
    const int lane = t & 63;
    const int wave = t >> 6;
    const int wm   = wave & 1;
    const int wn   = wave >> 1;
    const int l15  = lane & 15;
    const int quad = lane >> 4;

    const int srow    = lane >> 2;
    const int chunk_g = (lane & 3) ^ ((srow >> 1) & 3);
    const size_t aoff = (size_t)(gm0 + wave * 32 + srow) * K + chunk_g * 8;
    const size_t boff = (size_t)(gn0 + wave * 16 + srow) * K + chunk_g * 8;

    #pragma unroll
    for (int i = 0; i < 4; ++i)
        #pragma unroll
        for (int j = 0; j < 2; ++j)
            acc[i][j] = (f32x4){0.f, 0.f, 0.f, 0.f};

    for (int k0 = 0; k0 < K; k0 += 32) {
        gload_lds16(A + aoff + k0,                  &As[wave * 32][0]);
        gload_lds16(A + aoff + (size_t)16 * K + k0, &As[wave * 32 + 16][0]);
        gload_lds16(Bt + boff + k0,                 &Bs[wave * 16][0]);
        __syncthreads();

        bf16x8 af[4], bfr[2];
        #pragma unroll
        for (int mt = 0; mt < 4; ++mt) {
            const int row = wm * 64 + mt * 16 + l15;
            af[mt] = *(const bf16x8*)(&As[row][(quad ^ ((row >> 1) & 3)) * 8]);
        }
        #pragma unroll
        for (int nt = 0; nt < 2; ++nt) {
            const int row = wn * 32 + nt * 16 + l15;
            bfr[nt] = *(const bf16x8*)(&Bs[row][(quad ^ ((row >> 1) & 3)) * 8]);
        }
        #pragma unroll
        for (int mt = 0; mt < 4; ++mt)
            #pragma unroll
            for (int nt = 0; nt < 2; ++nt)
                acc[mt][nt] = mfma_16x16x32(af[mt], bfr[nt], acc[mt][nt]);

        __syncthreads();
    }
}

__global__ __launch_bounds__(256, 3) void ogemm_kernel(
    const bf16* __restrict__ Aw, const bf16* __restrict__ OWt,
    const float* __restrict__ o_b, float* __restrict__ C)
{
    __shared__ __align__(16) bf16 As[128][32];
    __shared__ __align__(16) bf16 Bs[64][32];

    const int gn0 = blockIdx.x * 64;
    const int gm0 = blockIdx.y * 128;

    f32x4 acc[4][2];
    gemm_core_128x64(Aw, OWt, 1024, gm0, gn0, As, Bs, acc);

    const int lane = threadIdx.x & 63;
    const int wave = threadIdx.x >> 6;
    const int wm   = wave & 1;
    const int wn   = wave >> 1;
    const int l15  = lane & 15;
    const int quad = lane >> 4;

    #pragma unroll
    for (int nt = 0; nt < 2; ++nt) {
        const int col = gn0 + wn * 32 + nt * 16 + l15;
        const float bb = o_b[col];
        #pragma unroll
        for (int mt = 0; mt < 4; ++mt) {
            #pragma unroll
            for (int r = 0; r < 4; ++r) {
                const int row = gm0 + wm * 64 + mt * 16 + quad * 4 + r;
                C[(size_t)row * 1024 + col] = acc[mt][nt][r] + bb;
            }
        }
    }
}

// ---------------------------------------------------------------------------
// Attention v7: r8 structure + raw v_exp_f32 + MFMA row-sum.
// block = (head, 128 q-rows), 4 waves, wave owns 32 q over the FULL kv range.
// K/V^T chunks staged once per block into double-buffered LDS
// (global_load_lds, XOR unit-swizzle), shared by 4 waves; 1 barrier/chunk.
// p = __builtin_amdgcn_exp2f(s) (Q pre-scaled by 1/32*log2e).
// Row-sums via MFMA with an all-ones B (replaces 32 v_add/chunk and the
// final 24-shuffle reduce; C/D layout replicates the sum across lanes).
// ---------------------------------------------------------------------------
__global__ __launch_bounds__(256) void attn_kernel(
    const bf16* __restrict__ Q, const bf16* __restrict__ K,
    const bf16* __restrict__ V, bf16* __restrict__ O)
{
    const int t    = threadIdx.x;
    const int lane = t & 63;
    const int wave = t >> 6;
    const int l15  = lane & 15;
    const int quad = lane >> 4;

    const int head = blockIdx.x;        // b*16 + h
    const int q0   = blockIdx.y * 128;
    const int b    = head >> 4;
    const int h    = head & 15;

    __shared__ __align__(16) bf16 Kb[2][64][64];   // [buf][kv][hd]
    __shared__ __align__(16) bf16 Vb[2][64][64];   // [buf][hd][kv]
    __shared__ __align__(16) bf16 P[4][32][72];    // per-wave P, pad 64->72

    const bf16* Qp  = Q + ((size_t)head * 1024 + q0 + wave * 32) * 64;
    const bf16* Kp  = K + (size_t)head * 1024 * 64;
    const bf16* Vtp = V + (size_t)head * 64 * 1024;

    const int r8  = lane >> 3;          // 0..7
    const int c8  = lane & 7;           // 0..7
    const int swz = (c8 ^ r8) * 8;      // fetch-side XOR unit swizzle

    bf16x8 aq[2][2];
    #pragma unroll
    for (int mt = 0; mt < 2; ++mt)
        #pragma unroll
        for (int kc = 0; kc < 2; ++kc)
            aq[mt][kc] = *(const bf16x8*)(Qp + (mt * 16 + l15) * 64 + kc * 32 + quad * 8);

    bf16x8 vones;
    #pragma unroll
    for (int j = 0; j < 8; ++j) vones[j] = (bf16)1.0f;

    f32x4 oacc[2][4];
    #pragma unroll
    for (int mt = 0; mt < 2; ++mt)
        #pragma unroll
        for (int nt = 0; nt < 4; ++nt)
            oacc[mt][nt] = (f32x4){0.f, 0.f, 0.f, 0.f};
    f32x4 lacc[2];
    lacc[0] = (f32x4){0.f, 0.f, 0.f, 0.f};
    lacc[1] = (f32x4){0.f, 0.f, 0.f, 0.f};

    #define STAGE(c, buf)                                                          \
        {                                                                          \
            const int kv0_ = (c) * 64;                                             \
            _Pragma("unroll")                                                      \
            for (int g = 0; g < 2; ++g) {                                          \
                const int R = wave * 16 + g * 8;                                   \
                gload_lds16(Kp + (size_t)(kv0_ + R + r8) * 64 + swz,               \
                            &Kb[buf][R][0]);                                       \
                gload_lds16(Vtp + (size_t)(R + r8) * 1024 + kv0_ + swz,            \
                            &Vb[buf][R][0]);                                       \
            }                                                                      \
        }

    STAGE(0, 0);

    const int sw = l15 & 7;             // read-side swizzle (row & 7)

    for (int c = 0; c < 16; ++c) {
        const int buf = c & 1;
        __syncthreads();
        if (c + 1 < 16) STAGE(c + 1, buf ^ 1);

        #pragma unroll
        for (int nt = 0; nt < 4; ++nt) {
            const bf16* krow = &Kb[buf][nt * 16 + l15][0];
            bf16x8 bk0 = *(const bf16x8*)(krow + (quad ^ sw) * 8);
            bf16x8 bk1 = *(const bf16x8*)(krow + ((quad + 4) ^ sw) * 8);
            #pragma unroll
            for (int mt = 0; mt < 2; ++mt) {
                f32x4 s = (f32x4){0.f, 0.f, 0.f, 0.f};
                s = mfma_16x16x32(aq[mt][0], bk0, s);
                s = mfma_16x16x32(aq[mt][1], bk1, s);
                #pragma unroll
                for (int r = 0; r < 4; ++r) {
                    const float e = __builtin_amdgcn_exp2f(s[r]);
                    P[wave][mt * 16 + quad * 4 + r][nt * 16 + l15] = (bf16)e;
                }
            }
        }

        #pragma unroll
        for (int mt = 0; mt < 2; ++mt) {
            bf16x8 pa0 = *(const bf16x8*)(&P[wave][mt * 16 + l15][quad * 8]);
            bf16x8 pa1 = *(const bf16x8*)(&P[wave][mt * 16 + l15][32 + quad * 8]);
            lacc[mt] = mfma_16x16x32(pa0, vones, lacc[mt]);
            lacc[mt] = mfma_16x16x32(pa1, vones, lacc[mt]);
            #pragma unroll
            for (int nt = 0; nt < 4; ++nt) {
                const bf16* vrow = &Vb[buf][nt * 16 + l15][0];
                bf16x8 bv0 = *(const bf16x8*)(vrow + (quad ^ sw) * 8);
                bf16x8 bv1 = *(const bf16x8*)(vrow + ((quad + 4) ^ sw) * 8);
                oacc[mt][nt] = mfma_16x16x32(pa0, bv0, oacc[mt][nt]);
                oacc[mt][nt] = mfma_16x16x32(pa1, bv1, oacc[mt][nt]);
            }
        }
    }
    #undef STAGE

    // lacc[mt][r] = row sum for row quad*4+r, replicated across all 16 cols
    #pragma unroll
    for (int mt = 0; mt < 2; ++mt) {
        const float invs[4] = {1.0f / lacc[mt][0], 1.0f / lacc[mt][1],
                               1.0f / lacc[mt][2], 1.0f / lacc[mt][3]};
        #pragma unroll
        for (int nt = 0; nt < 4; ++nt) {
            #pragma unroll
            for (int r = 0; r < 4; ++r) {
                const int row = q0 + wave * 32 + mt * 16 + quad * 4 + r;
                O[((size_t)b * 1024 + row) * 1024 + h * 64 + nt * 16 + l15] =
                    (bf16)(oacc[mt][nt][r] * invs[r]);
            }
        }
    }
}

// ---------------------------------------------------------------------------
// Host launcher — inputs/outputs FLOAT32 per reference; bf16 internal.
// ws (bf16 elems): l_bf 4M | v_bf 4M | QWt 1M | KVWt 2M | OWt 1M |
//                  Qh 4M | Kh 4M | Vt 4M | Aw 4M = 28M = 56 MB
// ---------------------------------------------------------------------------
extern "C" void kernel_launch(void* const* d_in, const int* in_sizes, int n_in,
                              void* d_out, int out_size, void* d_ws, size_t ws_size,
                              hipStream_t stream)
{
    const float* v_h = (const float*)d_in[0];
    const float* l_h = (const float*)d_in[1];
    const float* q_w = (const float*)d_in[2];
    const float* q_b = (const float*)d_in[3];
    const float* k_w = (const float*)d_in[4];
    const float* k_b = (const float*)d_in[5];
    const float* v_w = (const float*)d_in[6];
    const float* v_b = (const float*)d_in[7];
    const float* o_w = (const float*)d_in[8];
    const float* o_b = (const float*)d_in[9];
    float* out = (float*)d_out;

    const size_t SZ = (size_t)4096 * 1024;      // 4M
    const size_t WZ = (size_t)1024 * 1024;      // 1M

    bf16* l_bf = (bf16*)d_ws;
    bf16* v_bf = l_bf + SZ;
    bf16* QWt  = v_bf + SZ;
    bf16* KVWt = QWt + WZ;
    bf16* OWt  = KVWt + 2 * WZ;
    bf16* Qh   = OWt + WZ;      // (b,h,ls,64), pre-scaled by QSCALE
    bf16* Kh   = Qh + SZ;       // (b,h,vs,64)
    bf16* Vt   = Kh + SZ;       // (b,h,64,vs)
    bf16* Aw   = Vt + SZ;       // (b,ls,1024)

    prep_kernel<<<dim3(5120), 256, 0, stream>>>(
        l_h, v_h, q_w, k_w, v_w, o_w, l_bf, v_bf, QWt, KVWt, OWt);

    proj128_kernel<<<dim3(24, 32), 256, 0, stream>>>(
        l_bf, v_bf, QWt, KVWt, q_b, k_b, v_b, Qh, Kh, Vt);

    attn_kernel<<<dim3(64, 8), 256, 0, stream>>>(Qh, Kh, Vt, Aw);

    ogemm_kernel<<<dim3(16, 32), 256, 0, stream>>>(Aw, OWt, o_b, out);

    (void)in_sizes; (void)n_in; (void)out_size; (void)ws_size;
}